// Round 1
// baseline (174.875 us; speedup 1.0000x reference)
//
#include <hip/hip_runtime.h>
#include <math.h>

// Problem constants (fixed by the reference):
constexpr int B = 4, C = 64, N = 65536, K = 16;

// ---------------------------------------------------------------------------
// Kernel 1: transpose features [B, C, N] -> ft [B, N, C]
// 64x64 tiles through padded LDS; coalesced 256B reads and writes.
// ---------------------------------------------------------------------------
__global__ __launch_bounds__(256) void transpose_kernel(
    const float* __restrict__ f, float* __restrict__ ft) {
  __shared__ float tile[64][65];
  const int n0 = blockIdx.x * 64;
  const int b  = blockIdx.y;
  const float* fb  = f  + (size_t)b * C * N;
  float*       ftb = ft + (size_t)b * N * C;
  const int tx = threadIdx.x;  // 0..63 (along n for loads, along c for stores)
  const int ty = threadIdx.y;  // 0..3

#pragma unroll
  for (int i = 0; i < 64; i += 4) {
    const int c = ty + i;
    tile[c][tx] = fb[(size_t)c * N + n0 + tx];  // coalesced along n
  }
  __syncthreads();
#pragma unroll
  for (int i = 0; i < 64; i += 4) {
    const int n = ty + i;
    ftb[(size_t)(n0 + n) * C + tx] = tile[tx][n];  // coalesced along c
  }
}

// ---------------------------------------------------------------------------
// Kernel 2: gather-max. One wave per 64 consecutive n.
// lanes = c (0..63). For each n in tile: 16 broadcast index reads from LDS,
// 16 coalesced 256B gather loads from ft[b, idx, :], v_max accumulate.
// Result tile [64 n][64 c] transposed through padded LDS, stored as
// coalesced 256B rows of out[b, c, :].
// ---------------------------------------------------------------------------
__global__ __launch_bounds__(64) void gather_max_kernel(
    const float* __restrict__ ft, const int* __restrict__ nb,
    float* __restrict__ out) {
  __shared__ int   idx_s[K][64];
  __shared__ float tile[64][65];

  const int n0   = blockIdx.x * 64;
  const int b    = blockIdx.y;
  const int lane = threadIdx.x;  // 0..63

  const float* ftb = ft + (size_t)b * N * C;
  const int*   nbb = nb + (size_t)b * K * N;

  // Stage indices: coalesced 256B loads, one per k.
#pragma unroll
  for (int k = 0; k < K; ++k) {
    idx_s[k][lane] = nbb[(size_t)k * N + n0 + lane];
  }
  __syncthreads();

  for (int n = 0; n < 64; ++n) {
    float acc = -INFINITY;
#pragma unroll
    for (int k = 0; k < K; ++k) {
      const int idx = idx_s[k][n];          // broadcast (uniform address)
      const float v = ftb[(idx << 6) | lane];  // coalesced 256B gather row
      acc = fmaxf(acc, v);
    }
    tile[n][lane] = acc;  // bank: (n*65 + lane) -> distinct per lane, free
  }
  __syncthreads();

  float* outb = out + (size_t)b * C * N;
#pragma unroll
  for (int c = 0; c < 64; ++c) {
    // read tile[lane][c]: bank (lane + c) mod 32 -> 2-way, free
    outb[(size_t)c * N + n0 + lane] = tile[lane][c];
  }
}

// ---------------------------------------------------------------------------
// Fallback (workspace too small): direct gather, correct but slow.
// ---------------------------------------------------------------------------
__global__ __launch_bounds__(256) void naive_kernel(
    const float* __restrict__ f, const int* __restrict__ nb,
    float* __restrict__ out) {
  const int n = blockIdx.x * 256 + threadIdx.x;
  const int c = blockIdx.y;
  const int b = blockIdx.z;
  if (n >= N) return;
  const float* fb  = f  + (size_t)b * C * N + (size_t)c * N;
  const int*   nbb = nb + (size_t)b * K * N;
  float acc = -INFINITY;
#pragma unroll
  for (int k = 0; k < K; ++k) {
    acc = fmaxf(acc, fb[nbb[(size_t)k * N + n]]);
  }
  out[(size_t)b * C * N + (size_t)c * N + n] = acc;
}

extern "C" void kernel_launch(void* const* d_in, const int* in_sizes, int n_in,
                              void* d_out, int out_size, void* d_ws, size_t ws_size,
                              hipStream_t stream) {
  const float* f   = (const float*)d_in[0];
  const int*   nb  = (const int*)d_in[1];
  float*       out = (float*)d_out;

  const size_t need = (size_t)B * N * C * sizeof(float);
  if (ws_size >= need) {
    float* ft = (float*)d_ws;
    transpose_kernel<<<dim3(N / 64, B), dim3(64, 4), 0, stream>>>(f, ft);
    gather_max_kernel<<<dim3(N / 64, B), 64, 0, stream>>>(ft, nb, out);
  } else {
    naive_kernel<<<dim3((N + 255) / 256, C, B), 256, 0, stream>>>(f, nb, out);
  }
}